// Round 8
// baseline (233.954 us; speedup 1.0000x reference)
//
#include <hip/hip_runtime.h>
#include <hip/hip_bf16.h>
#include <stdint.h>

typedef __attribute__((ext_vector_type(8))) __bf16 bf16x8;
typedef __attribute__((ext_vector_type(4))) float  f32x4;

__device__ __forceinline__ ushort f2bf(float f) {
    union { float f; uint32_t u; } v; v.f = f;
    uint32_t u = v.u;
    uint32_t r = 0x7FFFu + ((u >> 16) & 1u);
    return (ushort)((u + r) >> 16);
}
__device__ __forceinline__ float bf2f(ushort u) {
    union { uint32_t u; float f; } v; v.u = ((uint32_t)u) << 16;
    return v.f;
}
__device__ __forceinline__ uint32_t pack2bf(float a, float b) {
    return (uint32_t)f2bf(a) | ((uint32_t)f2bf(b) << 16);
}

// async global->LDS, 16B per lane; LDS dest must be wave-uniform base + lane*16
typedef __attribute__((address_space(3))) uint32_t lds_u32_t;
typedef const __attribute__((address_space(1))) uint32_t glb_u32_t;
__device__ __forceinline__ void async_copy16(const void* g, void* l) {
    __builtin_amdgcn_global_load_lds((glb_u32_t*)g, (lds_u32_t*)l, 16, 0, 0);
}

// ------------- merged prep: mask_fused blocks [0,512) + convert blocks [512,7680) -------------
__global__ __launch_bounds__(256) void prep(
    const float* __restrict__ x, const float* __restrict__ wk,
    const float* __restrict__ wq, const float* __restrict__ wv,
    const float* __restrict__ m1, const float* __restrict__ m2,
    const int* __restrict__ rb,
    ushort* __restrict__ xb, ushort* __restrict__ wball, ushort* __restrict__ gth,
    float* __restrict__ ssb)
{
    __shared__ float As8[64 * 8];
    __shared__ float lmS[8 * 1024];
    const int tid = threadIdx.x;
    if (blockIdx.x == 0 && tid < 64) ssb[tid] = 0.f;   // replaces memset node
    if (blockIdx.x >= 512) {
        // ---- convert fp32 -> bf16 ----
        int i = (blockIdx.x - 512) * 256 + tid;
        const float* src; ushort* dst; int j;
        if (i < 1048576) { src = x; dst = xb; j = i; }
        else {
            int t = i - 1048576;
            int z = t >> 18;
            j = t & 262143;
            src = (z == 0) ? wk : (z == 1) ? wq : wv;
            dst = wball + z * 1048576;
        }
        float4 f = ((const float4*)src)[j];
        ushort4 o;
        o.x = f2bf(f.x); o.y = f2bf(f.y); o.z = f2bf(f.z); o.w = f2bf(f.w);
        ((ushort4*)dst)[j] = o;
        return;
    }
    // ---- mask: lm rows (8 per block) in LDS, then gather -> bf16 ----
    const int s0 = (blockIdx.x & 127) * 8;
    const int m = blockIdx.x >> 7;
    if (tid < 128) {
        int r = tid >> 1, half = tid & 1;
        *(float4*)&As8[r * 8 + half * 4] =
            *(const float4*)&m1[(m * 64 + r) * 1024 + s0 + half * 4];
    }
    __syncthreads();
    f32x4 acc8[8];
    #pragma unroll
    for (int s = 0; s < 8; s++) acc8[s] = (f32x4){0.f, 0.f, 0.f, 0.f};
    const float* m2b = m2 + m * 65536 + tid * 4;
    #pragma unroll 4
    for (int r = 0; r < 64; r++) {
        float4 b4 = *(const float4*)&m2b[r * 1024];
        f32x4 b = (f32x4){b4.x, b4.y, b4.z, b4.w};
        #pragma unroll
        for (int s = 0; s < 8; s++) acc8[s] += As8[r * 8 + s] * b;
    }
    #pragma unroll
    for (int s = 0; s < 8; s++)
        *(f32x4*)&lmS[s * 1024 + tid * 4] = acc8[s];
    __syncthreads();
    const int base = (m * 1024 + s0) * 1024;
    #pragma unroll
    for (int i = 0; i < 8; i++) {
        int c = tid + i * 256;
        int row = c >> 8, j = (c & 255) * 4;
        int4 idx = *(const int4*)&rb[base + row * 1024 + j];
        ushort4 o;
        o.x = f2bf(lmS[row * 1024 + (idx.x & 1023)] * 0.125f);
        o.y = f2bf(lmS[row * 1024 + (idx.y & 1023)] * 0.125f);
        o.z = f2bf(lmS[row * 1024 + (idx.z & 1023)] * 0.125f);
        o.w = f2bf(lmS[row * 1024 + (idx.w & 1023)] * 0.125f);
        *(ushort4*)&gth[base + row * 1024 + j] = o;
    }
}

// ---------------- QKV projection GEMM: Y = X @ W^T + b ----------------
// BK=64, XOR chunk-swizzle, double-buffered LDS, 1 barrier/iter.
// 1D grid 768, XCD swizzle: col-tile = g&7 (W cols L2-resident per XCD).
__global__ __launch_bounds__(256, 2) void proj_gemm(
    const ushort* __restrict__ xb, const ushort* __restrict__ wball,
    const float* __restrict__ bk, const float* __restrict__ bq, const float* __restrict__ bv,
    ushort* __restrict__ kd, ushort* __restrict__ qd, ushort* __restrict__ vd)
{
    __shared__ ushort As[2][128 * 64];
    __shared__ ushort Bs[2][128 * 64];
    const int g = blockIdx.x;
    const int col0 = (g & 7) * 128;
    const int t = g >> 3;
    const int row0 = (t & 31) * 128;
    const int z = t >> 5;
    const ushort* wb = wball + z * 1048576;
    const int tid = threadIdx.x;
    const int lane = tid & 63, wave = tid >> 6;
    const int quad = lane >> 4, m15 = lane & 15;
    const int wr = wave >> 1, wc = wave & 1;

    f32x4 acc[4][4];
    for (int i = 0; i < 4; i++)
        for (int j = 0; j < 4; j++) acc[i][j] = (f32x4){0.f, 0.f, 0.f, 0.f};

    auto stage = [&](int buf, int kk) {
        #pragma unroll
        for (int i = 0; i < 4; i++) {
            int c = tid + i * 256;
            int r = c >> 3, cjp = c & 7;
            int cj = cjp ^ (r & 7);
            async_copy16(&xb[(row0 + r) * 1024 + kk + cj * 8], &As[buf][c * 8]);
            async_copy16(&wb[(col0 + r) * 1024 + kk + cj * 8], &Bs[buf][c * 8]);
        }
    };

    stage(0, 0);
    for (int it = 0; it < 16; it++) {
        __syncthreads();
        if (it < 15) stage((it + 1) & 1, (it + 1) * 64);
        const ushort* Ab = As[it & 1];
        const ushort* Bb = Bs[it & 1];
        #pragma unroll
        for (int kh = 0; kh < 2; kh++) {
            bf16x8 af[4], bfv[4];
            #pragma unroll
            for (int fr = 0; fr < 4; fr++) {
                int row = wr * 64 + fr * 16 + m15;
                int q4 = kh * 4 + quad;
                af[fr] = *(const bf16x8*)&Ab[row * 64 + ((q4 ^ (row & 7)) * 8)];
            }
            #pragma unroll
            for (int fc = 0; fc < 4; fc++) {
                int row = wc * 64 + fc * 16 + m15;
                int q4 = kh * 4 + quad;
                bfv[fc] = *(const bf16x8*)&Bb[row * 64 + ((q4 ^ (row & 7)) * 8)];
            }
            #pragma unroll
            for (int fr = 0; fr < 4; fr++)
                #pragma unroll
                for (int fc = 0; fc < 4; fc++)
                    acc[fr][fc] = __builtin_amdgcn_mfma_f32_16x16x32_bf16(af[fr], bfv[fc], acc[fr][fc], 0, 0, 0);
        }
    }

    const float* bias = (z == 0) ? bk : (z == 1) ? bq : bv;
    ushort* dstA = (z == 0) ? kd : qd;
    for (int fr = 0; fr < 4; fr++) {
        int ibase = row0 + wr * 64 + fr * 16 + quad * 4;
        int b_ = ibase >> 10, s = ibase & 1023;
        for (int fc = 0; fc < 4; fc++) {
            int j = col0 + wc * 64 + fc * 16 + m15;
            int h = j >> 6, dh = j & 63;
            float bb = bias[j];
            if (z < 2) {
                for (int r = 0; r < 4; r++)
                    dstA[((b_ * 16 + h) * 1024 + (s + r)) * 64 + dh] = f2bf(acc[fr][fc][r] + bb);
            } else {
                ushort4 o;
                o.x = f2bf(acc[fr][fc][0] + bb);
                o.y = f2bf(acc[fr][fc][1] + bb);
                o.z = f2bf(acc[fr][fc][2] + bb);
                o.w = f2bf(acc[fr][fc][3] + bb);
                *(ushort4*)&vd[((b_ * 16 + h) * 64 + dh) * 1024 + s] = o;
            }
        }
    }
}

// ---------------- fused attention: O = (QK^T*mask) @ V ; ss = sum P^2 ----------------
// Transposed form: P^T = K·Q^T (lane holds 4 consecutive t for fixed s=sw).
// Mask read DIRECT from global (b64/lane, L2-hot via XCD swizzle) — no Ms staging.
// Async dbuf K/V staging, 1 barrier/tile; LDS 50.7 KB -> 3 blocks/CU.
__global__ __launch_bounds__(256, 3) void attention(
    const ushort* __restrict__ qd, const ushort* __restrict__ kd, const ushort* __restrict__ vd,
    const ushort* __restrict__ gth, float* __restrict__ O, float* __restrict__ ss)
{
    __shared__ ushort Ks[2][64 * 64];
    __shared__ ushort Vs[2][64 * 64];
    __shared__ ushort Ps[64 * 72];
    __shared__ float Osc[32 * 68];     // 2-pass O^T->O transpose scratch
    __shared__ float red[4];
    // XCD swizzle: 16 s-blocks of one bh -> same XCD (K/V/mask L2-resident)
    const int g = blockIdx.x;
    const int idx = g >> 3;
    const int s0 = (idx & 15) * 64;
    const int bh = (g & 7) + 8 * (idx >> 4);
    const int mm = bh & 3;
    const int tid = threadIdx.x, lane = tid & 63, wave = tid >> 6;
    const int quad = lane >> 4, m15 = lane & 15;
    const int sw = wave * 16 + m15;              // this lane's s-row (local)
    const int sw7 = m15 & 7;
    const ushort* mrow = gth + mm * 1048576 + (s0 + sw) * 1024;  // this lane's mask row

    // ---- prologue: Q tile (async, swizzled) into Ks[0]; pull B-frags ----
    #pragma unroll
    for (int i = 0; i < 2; i++) {
        int c = tid + i * 256;
        int r = c >> 3, cj = (c & 7) ^ (r & 7);
        async_copy16(&qd[(bh * 1024 + s0 + r) * 64 + cj * 8], &Ks[0][c * 8]);
    }
    __syncthreads();
    bf16x8 qf[2];
    #pragma unroll
    for (int kk = 0; kk < 2; kk++)
        qf[kk] = *(const bf16x8*)&Ks[0][sw * 64 + (((kk * 4 + quad) ^ sw7) * 8)];
    __syncthreads();

    f32x4 oacc[4];
    #pragma unroll
    for (int i = 0; i < 4; i++) oacc[i] = (f32x4){0.f, 0.f, 0.f, 0.f};
    float ssacc = 0.f;

    auto stage = [&](int buf, int t0) {
        #pragma unroll
        for (int i = 0; i < 2; i++) {
            int c = tid + i * 256;
            int r = c >> 3, cj = (c & 7) ^ (r & 7);
            async_copy16(&kd[(bh * 1024 + t0 + r) * 64 + cj * 8], &Ks[buf][c * 8]);
            async_copy16(&vd[(bh * 64 + r) * 1024 + t0 + cj * 8], &Vs[buf][c * 8]);
        }
    };

    stage(0, 0);
    for (int it = 0; it < 16; it++) {
        const int t0 = it * 64;
        __syncthreads();                 // tile `it` resident; prev readers done
        if (it < 15) stage((it + 1) & 1, t0 + 64);
        const ushort* Kb = Ks[it & 1];
        const ushort* Vb = Vs[it & 1];

        // mask loads (independent, issue early; L2-hot)
        ushort4 mv[4];
        #pragma unroll
        for (int tc = 0; tc < 4; tc++)
            mv[tc] = *(const ushort4*)&mrow[t0 + tc * 16 + quad * 4];

        // P^T = K·Q^T : lane -> s=sw, t = tc*16+quad*4+r
        f32x4 pacc[4];
        #pragma unroll
        for (int tc = 0; tc < 4; tc++) {
            f32x4 p = (f32x4){0.f, 0.f, 0.f, 0.f};
            #pragma unroll
            for (int kk = 0; kk < 2; kk++) {
                int row = tc * 16 + m15;
                bf16x8 a = *(const bf16x8*)&Kb[row * 64 + (((kk * 4 + quad) ^ (row & 7)) * 8)];
                p = __builtin_amdgcn_mfma_f32_16x16x32_bf16(a, qf[kk], p, 0, 0, 0);
            }
            pacc[tc] = p;
        }
        // mask multiply, square-sum, pack, P write (b64) — all wave-local
        #pragma unroll
        for (int tc = 0; tc < 4; tc++) {
            float p0 = pacc[tc][0] * bf2f(mv[tc].x);
            float p1 = pacc[tc][1] * bf2f(mv[tc].y);
            float p2 = pacc[tc][2] * bf2f(mv[tc].z);
            float p3 = pacc[tc][3] * bf2f(mv[tc].w);
            ssacc += p0 * p0 + p1 * p1 + p2 * p2 + p3 * p3;
            uint2 pw;
            pw.x = pack2bf(p0, p1);
            pw.y = pack2bf(p2, p3);
            *(uint2*)&Ps[sw * 72 + tc * 16 + quad * 4] = pw;
        }
        // O^T = V^T·P^T : A = V rows (dh), B = P[s=sw][8 consecutive t]
        bf16x8 pf[2];
        #pragma unroll
        for (int kk = 0; kk < 2; kk++)
            pf[kk] = *(const bf16x8*)&Ps[sw * 72 + kk * 32 + quad * 8];
        #pragma unroll
        for (int nc = 0; nc < 4; nc++) {
            #pragma unroll
            for (int kk = 0; kk < 2; kk++) {
                int row = nc * 16 + m15;
                bf16x8 a = *(const bf16x8*)&Vb[row * 64 + (((kk * 4 + quad) ^ (row & 7)) * 8)];
                oacc[nc] = __builtin_amdgcn_mfma_f32_16x16x32_bf16(a, pf[kk], oacc[nc], 0, 0, 0);
            }
        }
    }
    // epilogue: 2-pass transpose O^T (dh-major regs) -> O rows via 8.5 KB scratch
    #pragma unroll
    for (int half = 0; half < 2; half++) {
        __syncthreads();
        if ((wave >> 1) == half) {
            int row = (wave & 1) * 16 + m15;
            #pragma unroll
            for (int nc = 0; nc < 4; nc++)
                *(f32x4*)&Osc[row * 68 + nc * 16 + quad * 4] = oacc[nc];
        }
        __syncthreads();
        #pragma unroll
        for (int i = 0; i < 2; i++) {
            int c = tid + i * 256;
            int row = c >> 4, col = (c & 15) * 4;
            f32x4 v4 = *(const f32x4*)&Osc[row * 68 + col];
            *(f32x4*)&O[(bh * 1024 + s0 + half * 32 + row) * 64 + col] = v4;
        }
    }
    for (int off = 32; off; off >>= 1) ssacc += __shfl_down(ssacc, off, 64);
    if (lane == 0) red[wave] = ssacc;
    __syncthreads();
    if (tid == 0) atomicAdd(&ss[bh], red[0] + red[1] + red[2] + red[3]);
}

// ---------------- normalize + transpose to [B,S,H,DH] ----------------
__global__ __launch_bounds__(256) void normalize_out(const float* __restrict__ O,
                                                     const float* __restrict__ ss,
                                                     float* __restrict__ out)
{
    int gid = blockIdx.x * 256 + threadIdx.x;
    int e = gid * 4;
    int bh = e >> 16;
    float inv = 1.f / (sqrtf(ss[bh]) + 1e-8f);
    float4 v4 = *(const float4*)&O[e];
    int b_ = bh >> 4, h = bh & 15;
    int s = (e >> 6) & 1023, dh = e & 63;
    float4 o4 = {v4.x * inv, v4.y * inv, v4.z * inv, v4.w * inv};
    *(float4*)&out[((b_ * 1024 + s) * 16 + h) * 64 + dh] = o4;
}

extern "C" void kernel_launch(void* const* d_in, const int* in_sizes, int n_in,
                              void* d_out, int out_size, void* d_ws, size_t ws_size,
                              hipStream_t stream) {
    const float* x  = (const float*)d_in[0];
    const float* Wk = (const float*)d_in[1];
    const float* bk = (const float*)d_in[2];
    const float* Wq = (const float*)d_in[3];
    const float* bq = (const float*)d_in[4];
    const float* Wv = (const float*)d_in[5];
    const float* bv = (const float*)d_in[6];
    const float* m1 = (const float*)d_in[7];
    const float* m2 = (const float*)d_in[8];
    const int*   rb = (const int*)d_in[9];
    float* out = (float*)d_out;

    char* ws = (char*)d_ws;
    ushort* xb    = (ushort*)(ws);                  //  8 MB  [4096,1024] bf16
    ushort* wball = (ushort*)(ws + 8388608);        //  6 MB  3x[1024,1024] bf16
    ushort* kd    = (ushort*)(ws + 14680064);       //  8 MB  [B,H,S,DH] bf16
    ushort* qd    = (ushort*)(ws + 23068672);       //  8 MB
    ushort* vd    = (ushort*)(ws + 31457280);       //  8 MB  [B,H,DH,S] bf16
    float*  O     = (float*)(ws + 39845888);        // 16 MB  [B,H,S,DH] f32
    ushort* gth   = (ushort*)(ws + 56623104);       //  8 MB  [M,S,S] bf16
    float*  ssb   = (float*)(ws + 65011712);        // 64 f32

    prep<<<7680, 256, 0, stream>>>(x, Wk, Wq, Wv, m1, m2, rb, xb, wball, gth, ssb);
    proj_gemm<<<768, 256, 0, stream>>>(xb, wball, bk, bq, bv, kd, qd, vd);
    attention<<<1024, 256, 0, stream>>>(qd, kd, vd, gth, O, ssb);
    normalize_out<<<4096, 256, 0, stream>>>(O, ssb, out);
}

// Round 9
// 206.952 us; speedup vs baseline: 1.1305x; 1.1305x over previous
//
#include <hip/hip_runtime.h>
#include <hip/hip_bf16.h>
#include <stdint.h>

typedef __attribute__((ext_vector_type(8))) __bf16 bf16x8;
typedef __attribute__((ext_vector_type(4))) float  f32x4;
typedef __attribute__((ext_vector_type(2))) float  f32x2;

__device__ __forceinline__ ushort f2bf(float f) {
    union { float f; uint32_t u; } v; v.f = f;
    uint32_t u = v.u;
    uint32_t r = 0x7FFFu + ((u >> 16) & 1u);
    return (ushort)((u + r) >> 16);
}
// pack two f32 -> packed bf16 pair (round-half-up) via v_perm
__device__ __forceinline__ uint32_t pack2(f32x2 v) {
    union { float f; uint32_t u; } a, b; a.f = v[0]; b.f = v[1];
    return __builtin_amdgcn_perm(b.u + 0x8000u, a.u + 0x8000u, 0x07060302u);
}
__device__ __forceinline__ float u2f(uint32_t u) {
    union { uint32_t u; float f; } v; v.u = u;
    return v.f;
}

// async global->LDS, 16B per lane; LDS dest must be wave-uniform base + lane*16
typedef __attribute__((address_space(3))) uint32_t lds_u32_t;
typedef const __attribute__((address_space(1))) uint32_t glb_u32_t;
__device__ __forceinline__ void async_copy16(const void* g, void* l) {
    __builtin_amdgcn_global_load_lds((glb_u32_t*)g, (lds_u32_t*)l, 16, 0, 0);
}

// ------------- merged prep: mask_fused blocks [0,512) + convert blocks [512,7680) -------------
__global__ __launch_bounds__(256) void prep(
    const float* __restrict__ x, const float* __restrict__ wk,
    const float* __restrict__ wq, const float* __restrict__ wv,
    const float* __restrict__ m1, const float* __restrict__ m2,
    const int* __restrict__ rb,
    ushort* __restrict__ xb, ushort* __restrict__ wball, ushort* __restrict__ gth,
    float* __restrict__ ssb)
{
    __shared__ float As8[64 * 8];
    __shared__ float lmS[8 * 1024];
    const int tid = threadIdx.x;
    if (blockIdx.x == 0 && tid < 64) ssb[tid] = 0.f;   // replaces memset node
    if (blockIdx.x >= 512) {
        // ---- convert fp32 -> bf16 ----
        int i = (blockIdx.x - 512) * 256 + tid;
        const float* src; ushort* dst; int j;
        if (i < 1048576) { src = x; dst = xb; j = i; }
        else {
            int t = i - 1048576;
            int z = t >> 18;
            j = t & 262143;
            src = (z == 0) ? wk : (z == 1) ? wq : wv;
            dst = wball + z * 1048576;
        }
        float4 f = ((const float4*)src)[j];
        ushort4 o;
        o.x = f2bf(f.x); o.y = f2bf(f.y); o.z = f2bf(f.z); o.w = f2bf(f.w);
        ((ushort4*)dst)[j] = o;
        return;
    }
    // ---- mask: lm rows (8 per block) in LDS, then gather -> bf16 ----
    const int s0 = (blockIdx.x & 127) * 8;
    const int m = blockIdx.x >> 7;
    if (tid < 128) {
        int r = tid >> 1, half = tid & 1;
        *(float4*)&As8[r * 8 + half * 4] =
            *(const float4*)&m1[(m * 64 + r) * 1024 + s0 + half * 4];
    }
    __syncthreads();
    f32x4 acc8[8];
    #pragma unroll
    for (int s = 0; s < 8; s++) acc8[s] = (f32x4){0.f, 0.f, 0.f, 0.f};
    const float* m2b = m2 + m * 65536 + tid * 4;
    #pragma unroll 4
    for (int r = 0; r < 64; r++) {
        float4 b4 = *(const float4*)&m2b[r * 1024];
        f32x4 b = (f32x4){b4.x, b4.y, b4.z, b4.w};
        #pragma unroll
        for (int s = 0; s < 8; s++) acc8[s] += As8[r * 8 + s] * b;
    }
    #pragma unroll
    for (int s = 0; s < 8; s++)
        *(f32x4*)&lmS[s * 1024 + tid * 4] = acc8[s];
    __syncthreads();
    const int base = (m * 1024 + s0) * 1024;
    #pragma unroll
    for (int i = 0; i < 8; i++) {
        int c = tid + i * 256;
        int row = c >> 8, j = (c & 255) * 4;
        int4 idx = *(const int4*)&rb[base + row * 1024 + j];
        ushort4 o;
        o.x = f2bf(lmS[row * 1024 + (idx.x & 1023)] * 0.125f);
        o.y = f2bf(lmS[row * 1024 + (idx.y & 1023)] * 0.125f);
        o.z = f2bf(lmS[row * 1024 + (idx.z & 1023)] * 0.125f);
        o.w = f2bf(lmS[row * 1024 + (idx.w & 1023)] * 0.125f);
        *(ushort4*)&gth[base + row * 1024 + j] = o;
    }
}

// ---------------- QKV projection GEMM: Y = X @ W^T + b ----------------
// BK=64, XOR chunk-swizzle, double-buffered LDS, 1 barrier/iter.
// 1D grid 768, XCD swizzle: col-tile = g&7 (W cols L2-resident per XCD).
__global__ __launch_bounds__(256, 2) void proj_gemm(
    const ushort* __restrict__ xb, const ushort* __restrict__ wball,
    const float* __restrict__ bk, const float* __restrict__ bq, const float* __restrict__ bv,
    ushort* __restrict__ kd, ushort* __restrict__ qd, ushort* __restrict__ vd)
{
    __shared__ ushort As[2][128 * 64];
    __shared__ ushort Bs[2][128 * 64];
    const int g = blockIdx.x;
    const int col0 = (g & 7) * 128;
    const int t = g >> 3;
    const int row0 = (t & 31) * 128;
    const int z = t >> 5;
    const ushort* wb = wball + z * 1048576;
    const int tid = threadIdx.x;
    const int lane = tid & 63, wave = tid >> 6;
    const int quad = lane >> 4, m15 = lane & 15;
    const int wr = wave >> 1, wc = wave & 1;

    f32x4 acc[4][4];
    for (int i = 0; i < 4; i++)
        for (int j = 0; j < 4; j++) acc[i][j] = (f32x4){0.f, 0.f, 0.f, 0.f};

    auto stage = [&](int buf, int kk) {
        #pragma unroll
        for (int i = 0; i < 4; i++) {
            int c = tid + i * 256;
            int r = c >> 3, cjp = c & 7;
            int cj = cjp ^ (r & 7);
            async_copy16(&xb[(row0 + r) * 1024 + kk + cj * 8], &As[buf][c * 8]);
            async_copy16(&wb[(col0 + r) * 1024 + kk + cj * 8], &Bs[buf][c * 8]);
        }
    };

    stage(0, 0);
    for (int it = 0; it < 16; it++) {
        __syncthreads();
        if (it < 15) stage((it + 1) & 1, (it + 1) * 64);
        const ushort* Ab = As[it & 1];
        const ushort* Bb = Bs[it & 1];
        #pragma unroll
        for (int kh = 0; kh < 2; kh++) {
            bf16x8 af[4], bfv[4];
            #pragma unroll
            for (int fr = 0; fr < 4; fr++) {
                int row = wr * 64 + fr * 16 + m15;
                int q4 = kh * 4 + quad;
                af[fr] = *(const bf16x8*)&Ab[row * 64 + ((q4 ^ (row & 7)) * 8)];
            }
            #pragma unroll
            for (int fc = 0; fc < 4; fc++) {
                int row = wc * 64 + fc * 16 + m15;
                int q4 = kh * 4 + quad;
                bfv[fc] = *(const bf16x8*)&Bb[row * 64 + ((q4 ^ (row & 7)) * 8)];
            }
            #pragma unroll
            for (int fr = 0; fr < 4; fr++)
                #pragma unroll
                for (int fc = 0; fc < 4; fc++)
                    acc[fr][fc] = __builtin_amdgcn_mfma_f32_16x16x32_bf16(af[fr], bfv[fc], acc[fr][fc], 0, 0, 0);
        }
    }

    const float* bias = (z == 0) ? bk : (z == 1) ? bq : bv;
    ushort* dstA = (z == 0) ? kd : qd;
    for (int fr = 0; fr < 4; fr++) {
        int ibase = row0 + wr * 64 + fr * 16 + quad * 4;
        int b_ = ibase >> 10, s = ibase & 1023;
        for (int fc = 0; fc < 4; fc++) {
            int j = col0 + wc * 64 + fc * 16 + m15;
            int h = j >> 6, dh = j & 63;
            float bb = bias[j];
            if (z < 2) {
                for (int r = 0; r < 4; r++)
                    dstA[((b_ * 16 + h) * 1024 + (s + r)) * 64 + dh] = f2bf(acc[fr][fc][r] + bb);
            } else {
                ushort4 o;
                o.x = f2bf(acc[fr][fc][0] + bb);
                o.y = f2bf(acc[fr][fc][1] + bb);
                o.z = f2bf(acc[fr][fc][2] + bb);
                o.w = f2bf(acc[fr][fc][3] + bb);
                *(ushort4*)&vd[((b_ * 16 + h) * 64 + dh) * 1024 + s] = o;
            }
        }
    }
}

// ---------------- fused attention: O = (QK^T*mask) @ V ; ss = sum P^2 ----------------
// R7 structure (Ms async dbuf staging) + VALU-lean element phase:
// early b64 mask reads, packed f32x2 mul/fma, v_perm bf16 pack, direct O stores.
__global__ __launch_bounds__(256, 2) void attention(
    const ushort* __restrict__ qd, const ushort* __restrict__ kd, const ushort* __restrict__ vd,
    const ushort* __restrict__ gth, float* __restrict__ O, float* __restrict__ ss)
{
    __shared__ ushort Ks[2][64 * 64];
    __shared__ ushort Vs[2][64 * 64];
    __shared__ ushort Ms[2][64 * 64];
    __shared__ ushort Ps[64 * 72];
    __shared__ float red[4];
    // XCD swizzle: 16 s-blocks of one bh -> same XCD (K/V/mask L2-resident)
    const int g = blockIdx.x;
    const int idx = g >> 3;
    const int s0 = (idx & 15) * 64;
    const int bh = (g & 7) + 8 * (idx >> 4);
    const int mm = bh & 3;
    const int tid = threadIdx.x, lane = tid & 63, wave = tid >> 6;
    const int quad = lane >> 4, m15 = lane & 15;
    const int sw = wave * 16 + m15;              // this lane's s-row (local)
    const int sw7 = m15 & 7;
    const ushort* gbase = gth + mm * 1048576 + s0 * 1024;

    // ---- prologue: Q tile (async, swizzled) into Ks[0]; pull B-frags ----
    #pragma unroll
    for (int i = 0; i < 2; i++) {
        int c = tid + i * 256;
        int r = c >> 3, cj = (c & 7) ^ (r & 7);
        async_copy16(&qd[(bh * 1024 + s0 + r) * 64 + cj * 8], &Ks[0][c * 8]);
    }
    __syncthreads();
    bf16x8 qf[2];
    #pragma unroll
    for (int kk = 0; kk < 2; kk++)
        qf[kk] = *(const bf16x8*)&Ks[0][sw * 64 + (((kk * 4 + quad) ^ sw7) * 8)];
    __syncthreads();

    f32x4 oacc[4];
    #pragma unroll
    for (int i = 0; i < 4; i++) oacc[i] = (f32x4){0.f, 0.f, 0.f, 0.f};
    f32x2 ss2 = (f32x2){0.f, 0.f};

    auto stage = [&](int buf, int t0) {
        #pragma unroll
        for (int i = 0; i < 2; i++) {
            int c = tid + i * 256;
            int r = c >> 3, cj = (c & 7) ^ (r & 7);
            async_copy16(&kd[(bh * 1024 + t0 + r) * 64 + cj * 8], &Ks[buf][c * 8]);
            async_copy16(&vd[(bh * 64 + r) * 1024 + t0 + cj * 8], &Vs[buf][c * 8]);
            async_copy16(&gbase[r * 1024 + t0 + cj * 8],          &Ms[buf][c * 8]);
        }
    };

    stage(0, 0);
    for (int it = 0; it < 16; it++) {
        __syncthreads();                 // tile `it` resident; prev readers done
        if (it < 15) stage((it + 1) & 1, (it + 1) * 64);
        const ushort* Kb = Ks[it & 1];
        const ushort* Vb = Vs[it & 1];
        const ushort* Mb = Ms[it & 1];

        // early mask reads (b64/lane, wave-local rows) — latency hides under QK^T
        uint2 mraw[4];
        #pragma unroll
        for (int tc = 0; tc < 4; tc++) {
            int ch = (tc * 2 + (quad >> 1)) ^ sw7;
            mraw[tc] = *(const uint2*)&Mb[sw * 64 + ch * 8 + (quad & 1) * 4];
        }

        // P^T = K·Q^T : lane -> s=sw, t = tc*16+quad*4+r
        f32x4 pacc[4];
        #pragma unroll
        for (int tc = 0; tc < 4; tc++) {
            f32x4 p = (f32x4){0.f, 0.f, 0.f, 0.f};
            #pragma unroll
            for (int kk = 0; kk < 2; kk++) {
                int row = tc * 16 + m15;
                bf16x8 a = *(const bf16x8*)&Kb[row * 64 + (((kk * 4 + quad) ^ (row & 7)) * 8)];
                p = __builtin_amdgcn_mfma_f32_16x16x32_bf16(a, qf[kk], p, 0, 0, 0);
            }
            pacc[tc] = p;
        }
        // packed mask-mult + square-sum + bf16 pack + b64 P write (all wave-local)
        #pragma unroll
        for (int tc = 0; tc < 4; tc++) {
            uint2 w = mraw[tc];
            f32x2 m01 = (f32x2){u2f(w.x << 16), u2f(w.x & 0xFFFF0000u)};
            f32x2 m23 = (f32x2){u2f(w.y << 16), u2f(w.y & 0xFFFF0000u)};
            f32x2 p01 = (f32x2){pacc[tc][0], pacc[tc][1]} * m01;
            f32x2 p23 = (f32x2){pacc[tc][2], pacc[tc][3]} * m23;
            ss2 += p01 * p01;
            ss2 += p23 * p23;
            uint2 pw;
            pw.x = pack2(p01);
            pw.y = pack2(p23);
            *(uint2*)&Ps[sw * 72 + tc * 16 + quad * 4] = pw;
        }
        // O^T = V^T·P^T : A = V rows (dh), B = P[s=sw][8 consecutive t]
        bf16x8 pf[2];
        #pragma unroll
        for (int kk = 0; kk < 2; kk++)
            pf[kk] = *(const bf16x8*)&Ps[sw * 72 + kk * 32 + quad * 8];
        #pragma unroll
        for (int nc = 0; nc < 4; nc++) {
            #pragma unroll
            for (int kk = 0; kk < 2; kk++) {
                int row = nc * 16 + m15;
                bf16x8 a = *(const bf16x8*)&Vb[row * 64 + (((kk * 4 + quad) ^ (row & 7)) * 8)];
                oacc[nc] = __builtin_amdgcn_mfma_f32_16x16x32_bf16(a, pf[kk], oacc[nc], 0, 0, 0);
            }
        }
    }
    // direct O stores: lane holds O[s=sw][dh = nc*16+quad*4 .. +3]
    #pragma unroll
    for (int nc = 0; nc < 4; nc++)
        *(f32x4*)&O[(bh * 1024 + s0 + sw) * 64 + nc * 16 + quad * 4] = oacc[nc];

    float ssacc = ss2[0] + ss2[1];
    for (int off = 32; off; off >>= 1) ssacc += __shfl_down(ssacc, off, 64);
    if (lane == 0) red[wave] = ssacc;
    __syncthreads();
    if (tid == 0) atomicAdd(&ss[bh], red[0] + red[1] + red[2] + red[3]);
}

// ---------------- normalize + transpose to [B,S,H,DH] ----------------
__global__ __launch_bounds__(256) void normalize_out(const float* __restrict__ O,
                                                     const float* __restrict__ ss,
                                                     float* __restrict__ out)
{
    int gid = blockIdx.x * 256 + threadIdx.x;
    int e = gid * 4;
    int bh = e >> 16;
    float inv = 1.f / (sqrtf(ss[bh]) + 1e-8f);
    float4 v4 = *(const float4*)&O[e];
    int b_ = bh >> 4, h = bh & 15;
    int s = (e >> 6) & 1023, dh = e & 63;
    float4 o4 = {v4.x * inv, v4.y * inv, v4.z * inv, v4.w * inv};
    *(float4*)&out[((b_ * 1024 + s) * 16 + h) * 64 + dh] = o4;
}

extern "C" void kernel_launch(void* const* d_in, const int* in_sizes, int n_in,
                              void* d_out, int out_size, void* d_ws, size_t ws_size,
                              hipStream_t stream) {
    const float* x  = (const float*)d_in[0];
    const float* Wk = (const float*)d_in[1];
    const float* bk = (const float*)d_in[2];
    const float* Wq = (const float*)d_in[3];
    const float* bq = (const float*)d_in[4];
    const float* Wv = (const float*)d_in[5];
    const float* bv = (const float*)d_in[6];
    const float* m1 = (const float*)d_in[7];
    const float* m2 = (const float*)d_in[8];
    const int*   rb = (const int*)d_in[9];
    float* out = (float*)d_out;

    char* ws = (char*)d_ws;
    ushort* xb    = (ushort*)(ws);                  //  8 MB  [4096,1024] bf16
    ushort* wball = (ushort*)(ws + 8388608);        //  6 MB  3x[1024,1024] bf16
    ushort* kd    = (ushort*)(ws + 14680064);       //  8 MB  [B,H,S,DH] bf16
    ushort* qd    = (ushort*)(ws + 23068672);       //  8 MB
    ushort* vd    = (ushort*)(ws + 31457280);       //  8 MB  [B,H,DH,S] bf16
    float*  O     = (float*)(ws + 39845888);        // 16 MB  [B,H,S,DH] f32
    ushort* gth   = (ushort*)(ws + 56623104);       //  8 MB  [M,S,S] bf16
    float*  ssb   = (float*)(ws + 65011712);        // 64 f32

    prep<<<7680, 256, 0, stream>>>(x, Wk, Wq, Wv, m1, m2, rb, xb, wball, gth, ssb);
    proj_gemm<<<768, 256, 0, stream>>>(xb, wball, bk, bq, bv, kd, qd, vd);
    attention<<<1024, 256, 0, stream>>>(qd, kd, vd, gth, O, ssb);
    normalize_out<<<4096, 256, 0, stream>>>(O, ssb, out);
}